// Round 1
// baseline (845.543 us; speedup 1.0000x reference)
//
#include <hip/hip_runtime.h>
#include <hip/hip_bf16.h>

#define EPS 1e-5f

// B=64, C=256, L=4096. Rows 0..63 = multi (softmax(w_channel)), 64..111 = skip (w_down), 112..127 pad.

// ---- K1: per (b,c) mean / rstd over L ----
__global__ __launch_bounds__(256) void k1_stats(const float* __restrict__ x,
                                                float* __restrict__ mean,
                                                float* __restrict__ rstd) {
    int row = blockIdx.x;                       // b*256 + c
    const float* xr = x + (size_t)row * 4096;
    int t = threadIdx.x;
    float s = 0.f, ss = 0.f;
#pragma unroll
    for (int i = 0; i < 4; ++i) {
        float4 v = *(const float4*)(xr + t * 4 + i * 1024);
        s  += v.x + v.y + v.z + v.w;
        ss += v.x * v.x + v.y * v.y + v.z * v.z + v.w * v.w;
    }
    for (int off = 32; off > 0; off >>= 1) {
        s  += __shfl_down(s, off, 64);
        ss += __shfl_down(ss, off, 64);
    }
    __shared__ float red[8];
    int wid = t >> 6, lane = t & 63;
    if (lane == 0) { red[wid * 2] = s; red[wid * 2 + 1] = ss; }
    __syncthreads();
    if (t == 0) {
        float S  = red[0] + red[2] + red[4] + red[6];
        float SS = red[1] + red[3] + red[5] + red[7];
        float m = S * (1.f / 4096.f);
        float v = fmaxf(SS * (1.f / 4096.f) - m * m, 0.f);
        mean[row] = m;
        rstd[row] = rsqrtf(v + EPS);
    }
}

// ---- K2: fold softmax(w_channel) and w_down with per-(b,c) norm into Wc[b][128][256] + bias[b][128] ----
__global__ __launch_bounds__(256) void k2_prep(const float* __restrict__ wch,
                                               const float* __restrict__ wdn,
                                               const float* __restrict__ mean,
                                               const float* __restrict__ rstd,
                                               float* __restrict__ Wc,
                                               float* __restrict__ bias) {
    int b = blockIdx.x, c = threadIdx.x;        // 256 threads, one per input channel
    __shared__ float sb[128];
    if (c < 128) sb[c] = 0.f;
    __syncthreads();
    float m = mean[b * 256 + c];
    float s = rstd[b * 256 + c];
    float mx = -1e30f;
    for (int o = 0; o < 64; ++o) mx = fmaxf(mx, wch[o * 256 + c]);
    float sum = 0.f;
    for (int o = 0; o < 64; ++o) sum += __expf(wch[o * 256 + c] - mx);
    float inv = 1.f / sum;
    float* Wb = Wc + (size_t)b * 128 * 256;
    for (int o = 0; o < 64; ++o) {
        float wp = __expf(wch[o * 256 + c] - mx) * inv * s;
        Wb[o * 256 + c] = wp;
        atomicAdd(&sb[o], -wp * m);
    }
    for (int j = 0; j < 48; ++j) {
        float wp = wdn[j * 256 + c] * s;
        Wb[(64 + j) * 256 + c] = wp;
        atomicAdd(&sb[64 + j], -wp * m);
    }
    for (int r = 112; r < 128; ++r) Wb[r * 256 + c] = 0.f;
    __syncthreads();
    if (c < 128) bias[b * 128 + c] = sb[c];
}

// ---- K3: per (b, l-tile of 64): P[128][64] = Wc[b] @ x[b] + bias; apply symbolic funcs; write img/skip; accumulate stats ----
__global__ __launch_bounds__(256) void k3_main(const float* __restrict__ x,
                                               const float* __restrict__ Wc,
                                               const float* __restrict__ bias,
                                               float* __restrict__ imgw,
                                               float* __restrict__ skipw,
                                               float* __restrict__ gsum,
                                               float* __restrict__ gss) {
    int lt = blockIdx.x;          // 0..63
    int b  = blockIdx.y;          // 0..63
    int l0 = lt * 64;
    int t  = threadIdx.x;
    int tx = t & 15, ty = t >> 4; // thread tile: o = ty*8..ty*8+7, l = l0 + tx*4..+3

    __shared__ float xs[32][64];        // c-chunk x l
    __shared__ float wsm[32][132];      // c-chunk x o (padded stride, 16B aligned rows)
    __shared__ float s_sum[48], s_ss[48];
    if (t < 48) { s_sum[t] = 0.f; s_ss[t] = 0.f; }

    float acc[8][4];
#pragma unroll
    for (int r = 0; r < 8; ++r)
#pragma unroll
        for (int k = 0; k < 4; ++k) acc[r][k] = 0.f;

    const float* xb = x + (size_t)b * 256 * 4096 + l0;
    const float* Wb = Wc + (size_t)b * 128 * 256;

    for (int cc = 0; cc < 8; ++cc) {
        int c0 = cc * 32;
        {   // x chunk: 32 rows x 64 cols, coalesced float4
            int row = t >> 4;
            int col = (t & 15) * 4;
            *(float4*)&xs[row][col]      = *(const float4*)(xb + (size_t)(c0 + row) * 4096 + col);
            *(float4*)&xs[row + 16][col] = *(const float4*)(xb + (size_t)(c0 + row + 16) * 4096 + col);
        }
        {   // W chunk, transposed into wsm[c][o]
            int ci = t & 31;
            int o4 = (t >> 5) * 4;
#pragma unroll
            for (int it = 0; it < 4; ++it) {
                int o = o4 + it * 32;
                float4 wv;
                wv.x = Wb[(o + 0) * 256 + c0 + ci];
                wv.y = Wb[(o + 1) * 256 + c0 + ci];
                wv.z = Wb[(o + 2) * 256 + c0 + ci];
                wv.w = Wb[(o + 3) * 256 + c0 + ci];
                *(float4*)&wsm[ci][o] = wv;
            }
        }
        __syncthreads();
#pragma unroll 8
        for (int c = 0; c < 32; ++c) {
            float4 xv = *(const float4*)&xs[c][tx * 4];
            float4 w0 = *(const float4*)&wsm[c][ty * 8];
            float4 w1 = *(const float4*)&wsm[c][ty * 8 + 4];
            float w[8] = {w0.x, w0.y, w0.z, w0.w, w1.x, w1.y, w1.z, w1.w};
#pragma unroll
            for (int r = 0; r < 8; ++r) {
                acc[r][0] += w[r] * xv.x;
                acc[r][1] += w[r] * xv.y;
                acc[r][2] += w[r] * xv.z;
                acc[r][3] += w[r] * xv.w;
            }
        }
        __syncthreads();
    }
#pragma unroll
    for (int r = 0; r < 8; ++r) {
        float bb = bias[b * 128 + ty * 8 + r];
#pragma unroll
        for (int k = 0; k < 4; ++k) acc[r][k] += bb;
    }

    if (ty < 8) {
        // multi channels 8*ty .. 8*ty+7 -> img channels 6*ty .. 6*ty+5
        int jb = ty * 6;
        float img[6][4];
#pragma unroll
        for (int k = 0; k < 4; ++k) {
            img[0][k] = acc[0][k] + acc[1][k];
            img[1][k] = acc[2][k] * acc[3][k];
            img[2][k] = __sinf(acc[4][k]);
            img[3][k] = __cosf(acc[5][k]);
            float xt = acc[6][k];
            float e  = __expf(-2.f * fabsf(xt));
            img[4][k] = copysignf((1.f - e) / (1.f + e), xt);
            img[5][k] = acc[7][k];
        }
#pragma unroll
        for (int f = 0; f < 6; ++f) {
            float4 v = make_float4(img[f][0], img[f][1], img[f][2], img[f][3]);
            *(float4*)(imgw + (size_t)(b * 48 + jb + f) * 4096 + l0 + tx * 4) = v;
            float ls  = v.x + v.y + v.z + v.w;
            float lss = v.x * v.x + v.y * v.y + v.z * v.z + v.w * v.w;
            atomicAdd(&s_sum[jb + f], ls);
            atomicAdd(&s_ss[jb + f], lss);
        }
    } else if (ty < 14) {
        int sj = (ty - 8) * 8;
#pragma unroll
        for (int r = 0; r < 8; ++r) {
            float4 v = make_float4(acc[r][0], acc[r][1], acc[r][2], acc[r][3]);
            *(float4*)(skipw + (size_t)(b * 48 + sj + r) * 4096 + l0 + tx * 4) = v;
        }
    }
    __syncthreads();
    if (t < 48) {
        atomicAdd(&gsum[b * 48 + t], s_sum[t]);
        atomicAdd(&gss[b * 48 + t],  s_ss[t]);
    }
}

// ---- K4: finalize: inorm(img) * renorm-chain + skip ----
__global__ __launch_bounds__(256) void k4_final(const float* __restrict__ imgw,
                                                const float* __restrict__ skipw,
                                                const float* __restrict__ gsum,
                                                const float* __restrict__ gss,
                                                float* __restrict__ out) {
    int j = blockIdx.x, b = blockIdx.y;
    int bj = b * 48 + j;
    float m = gsum[bj] * (1.f / 4096.f);
    float v = fmaxf(gss[bj] * (1.f / 4096.f) - m * m, 0.f);
    float rs = rsqrtf(v + EPS);
    // channel j is re-inormed (47-j) more times; mean stays 0, variance evolves v -> v/(v+eps)
    float g = 1.f;
    float vv = v / (v + EPS);
    for (int k = 0; k < 47 - j; ++k) {
        g *= rsqrtf(vv + EPS);
        vv = vv / (vv + EPS);
    }
    float sc = rs * g;
    const float* ir = imgw  + (size_t)bj * 4096;
    const float* sr = skipw + (size_t)bj * 4096;
    float* orow = out + (size_t)bj * 4096;
    int t = threadIdx.x;
#pragma unroll
    for (int i = 0; i < 4; ++i) {
        int idx = t * 4 + i * 1024;
        float4 a  = *(const float4*)(ir + idx);
        float4 s4 = *(const float4*)(sr + idx);
        float4 o;
        o.x = (a.x - m) * sc + s4.x;
        o.y = (a.y - m) * sc + s4.y;
        o.z = (a.z - m) * sc + s4.z;
        o.w = (a.w - m) * sc + s4.w;
        *(float4*)(orow + idx) = o;
    }
}

extern "C" void kernel_launch(void* const* d_in, const int* in_sizes, int n_in,
                              void* d_out, int out_size, void* d_ws, size_t ws_size,
                              hipStream_t stream) {
    const float* x   = (const float*)d_in[0];   // [64,256,4096]
    const float* wch = (const float*)d_in[1];   // [64,256]
    const float* wdn = (const float*)d_in[2];   // [48,256]
    float* out = (float*)d_out;                 // [64,48,4096]

    float* mean  = (float*)d_ws;                        // 16384
    float* rstd  = mean + 16384;                        // 16384
    float* Wc    = rstd + 16384;                        // 64*128*256
    float* bias  = Wc + (size_t)64 * 128 * 256;         // 8192
    float* imgw  = bias + 8192;                         // 64*48*4096
    float* skipw = imgw + (size_t)64 * 48 * 4096;       // 64*48*4096
    float* gsum  = skipw + (size_t)64 * 48 * 4096;      // 3072
    float* gss   = gsum + 3072;                         // 3072

    hipMemsetAsync(gsum, 0, 2 * 3072 * sizeof(float), stream);
    k1_stats<<<dim3(16384), dim3(256), 0, stream>>>(x, mean, rstd);
    k2_prep<<<dim3(64), dim3(256), 0, stream>>>(wch, wdn, mean, rstd, Wc, bias);
    k3_main<<<dim3(64, 64), dim3(256), 0, stream>>>(x, Wc, bias, imgw, skipw, gsum, gss);
    k4_final<<<dim3(48, 64), dim3(256), 0, stream>>>(imgw, skipw, gsum, gss, out);
}

// Round 2
// 551.405 us; speedup vs baseline: 1.5334x; 1.5334x over previous
//
#include <hip/hip_runtime.h>
#include <hip/hip_bf16.h>

#define EPS 1e-5f

typedef unsigned int u32;
typedef unsigned short u16;
typedef __attribute__((ext_vector_type(8))) short bf16x8;
typedef __attribute__((ext_vector_type(4))) float f32x4;

__device__ __forceinline__ u32 f2bf(float f) {
    u32 u = __float_as_uint(f);
    u += 0x7FFFu + ((u >> 16) & 1u);      // RNE
    return u >> 16;
}
__device__ __forceinline__ float bf2f(u32 h) {
    return __uint_as_float(h << 16);
}

// ---- K1: per (b,c) mean / rstd over L ----  (unchanged from R1: passed)
__global__ __launch_bounds__(256) void k1_stats(const float* __restrict__ x,
                                                float* __restrict__ mean,
                                                float* __restrict__ rstd) {
    int row = blockIdx.x;                       // b*256 + c
    const float* xr = x + (size_t)row * 4096;
    int t = threadIdx.x;
    float s = 0.f, ss = 0.f;
#pragma unroll
    for (int i = 0; i < 4; ++i) {
        float4 v = *(const float4*)(xr + t * 4 + i * 1024);
        s  += v.x + v.y + v.z + v.w;
        ss += v.x * v.x + v.y * v.y + v.z * v.z + v.w * v.w;
    }
    for (int off = 32; off > 0; off >>= 1) {
        s  += __shfl_down(s, off, 64);
        ss += __shfl_down(ss, off, 64);
    }
    __shared__ float red[8];
    int wid = t >> 6, lane = t & 63;
    if (lane == 0) { red[wid * 2] = s; red[wid * 2 + 1] = ss; }
    __syncthreads();
    if (t == 0) {
        float S  = red[0] + red[2] + red[4] + red[6];
        float SS = red[1] + red[3] + red[5] + red[7];
        float m = S * (1.f / 4096.f);
        float v = fmaxf(SS * (1.f / 4096.f) - m * m, 0.f);
        mean[row] = m;
        rstd[row] = rsqrtf(v + EPS);
    }
}

// ---- K2: fold softmax(w_channel), w_down with per-(b,c) norm into bf16 Wc[b][128][256] + bias[b][128].
//      No shared-memory atomics: per-row block reduction via shuffles. Also zeros gsum/gss.
__global__ __launch_bounds__(256) void k2_prep(const float* __restrict__ wch,
                                               const float* __restrict__ wdn,
                                               const float* __restrict__ mean,
                                               const float* __restrict__ rstd,
                                               u16* __restrict__ Wc,
                                               float* __restrict__ bias,
                                               float* __restrict__ gsum,
                                               float* __restrict__ gss) {
    int b = blockIdx.x, c = threadIdx.x;
    float m = mean[b * 256 + c];
    float s = rstd[b * 256 + c];
    float mx = -1e30f;
    for (int o = 0; o < 64; ++o) mx = fmaxf(mx, wch[o * 256 + c]);
    float sum = 0.f;
    for (int o = 0; o < 64; ++o) sum += __expf(wch[o * 256 + c] - mx);
    float inv = 1.f / sum;
    u16* Wb = Wc + (size_t)b * 128 * 256;
    __shared__ float red[8];                    // double-buffered by row parity
    int wid = c >> 6, lane = c & 63;
    for (int mr = 0; mr < 128; ++mr) {
        float w;
        if (mr < 64)        w = __expf(wch[mr * 256 + c] - mx) * inv;
        else if (mr < 112)  w = wdn[(mr - 64) * 256 + c];
        else                w = 0.f;
        float ws = w * s;
        u32 hb = f2bf(ws);
        Wb[mr * 256 + c] = (u16)hb;
        float p = bf2f(hb) * m;                 // use rounded weight for consistency
        for (int off = 32; off > 0; off >>= 1) p += __shfl_down(p, off, 64);
        if (lane == 0) red[(mr & 1) * 4 + wid] = p;
        __syncthreads();
        if (c == 0) {
            int o4 = (mr & 1) * 4;
            bias[b * 128 + mr] = -(red[o4] + red[o4 + 1] + red[o4 + 2] + red[o4 + 3]);
        }
    }
    if (c < 48) { gsum[b * 48 + c] = 0.f; gss[b * 48 + c] = 0.f; }
}

// ---- K3: MFMA GEMM P[128][128] = Wc[b] @ x-tile + bias, fused symbolic funcs + stats ----
// LDS layouts (u32 words, row stride 36 words = 72 bf16, +8 bf16 pad):
//   Wl[m][kp]  : m 0..127, kp 0..31 (bf16 pair per word, k = chunk-local c)
//   xTl[n][kp] : n 0..127 (= l within tile), kp 0..31   -- transposed during staging
#define LSTR 36
__global__ __launch_bounds__(256, 4) void k3_main(const float* __restrict__ x,
                                                  const u16* __restrict__ Wc,
                                                  const float* __restrict__ bias,
                                                  u16* __restrict__ imgw,
                                                  u16* __restrict__ skipw,
                                                  float* __restrict__ gsum,
                                                  float* __restrict__ gss) {
    int lt = blockIdx.x;          // 0..31  (128-wide l tiles)
    int b  = blockIdx.y;          // 0..63
    int n0blk = lt * 128;
    int t = threadIdx.x;
    int w = t >> 6, u = t & 63;
    int lane16 = u & 15, q = u >> 4;
    int m0  = (w & 1) * 64;       // wave m-quadrant
    int n0w = (w >> 1) * 64;      // wave n-quadrant

    __shared__ u32 Wl[128 * LSTR];
    __shared__ u32 xTl[128 * LSTR];
    __shared__ float sbias[128];

    if (t < 128) sbias[t] = bias[b * 128 + t];

    f32x4 acc[4][4];
#pragma unroll
    for (int mt = 0; mt < 4; ++mt)
#pragma unroll
        for (int nt = 0; nt < 4; ++nt) acc[mt][nt] = (f32x4){0.f, 0.f, 0.f, 0.f};

    const float* xb = x + (size_t)b * 256 * 4096 + n0blk;
    const u16* Wb = Wc + (size_t)b * 128 * 256;

    for (int cc = 0; cc < 4; ++cc) {
        int c0 = cc * 64;
        if (cc) __syncthreads();
        // ---- stage W chunk: 1024 slots of 16B, coalesced global, b128 LDS write
#pragma unroll
        for (int p = 0; p < 4; ++p) {
            int sl = t + 256 * p;
            int m = sl >> 3, kq = sl & 7;
            uint4 v = *(const uint4*)(Wb + m * 256 + c0 + 8 * kq);
            *(uint4*)&Wl[m * LSTR + 4 * kq] = v;
        }
        // ---- stage x chunk transposed: slot = (kp 0..31, nqq 0..31); lane kp = u&31 -> conflict-free b32 writes
#pragma unroll
        for (int p = 0; p < 4; ++p) {
            int sl = t + 256 * p;
            int kp = sl & 31, nqq = sl >> 5;
            const float* xr = xb + (size_t)(c0 + 2 * kp) * 4096 + 4 * nqq;
            float4 r0 = *(const float4*)xr;
            float4 r1 = *(const float4*)(xr + 4096);
            int base = (4 * nqq) * LSTR + kp;
            xTl[base]            = f2bf(r0.x) | (f2bf(r1.x) << 16);
            xTl[base + LSTR]     = f2bf(r0.y) | (f2bf(r1.y) << 16);
            xTl[base + 2 * LSTR] = f2bf(r0.z) | (f2bf(r1.z) << 16);
            xTl[base + 3 * LSTR] = f2bf(r0.w) | (f2bf(r1.w) << 16);
        }
        __syncthreads();
        // ---- compute: 2 k-steps of 32 per chunk
#pragma unroll
        for (int kk = 0; kk < 2; ++kk) {
            int kwo = kk * 16 + q * 4;
            bf16x8 af[4], bfr[4];
#pragma unroll
            for (int mt = 0; mt < 4; ++mt)
                af[mt] = *(bf16x8*)&Wl[(m0 + 16 * mt + lane16) * LSTR + kwo];
#pragma unroll
            for (int nt = 0; nt < 4; ++nt)
                bfr[nt] = *(bf16x8*)&xTl[(n0w + 16 * nt + lane16) * LSTR + kwo];
#pragma unroll
            for (int mt = 0; mt < 4; ++mt)
#pragma unroll
                for (int nt = 0; nt < 4; ++nt)
                    acc[mt][nt] = __builtin_amdgcn_mfma_f32_16x16x32_bf16(af[mt], bfr[nt], acc[mt][nt], 0, 0, 0);
        }
    }
    __syncthreads();

    // ---- epilogue ----
    int jb = b * 48;
    if (m0 == 0) {
        // multi rows: o = 16*mt + 4*q + r ; 8 o's per 6 img channels
        int g2 = q >> 1, qo = q & 1;
#pragma unroll
        for (int mt = 0; mt < 4; ++mt) {
            int g = 2 * mt + g2;
            int j0 = 6 * g + (qo ? 2 : 0);
            int cnt = qo ? 4 : 2;
            float b0 = sbias[16 * mt + 4 * q + 0];
            float b1 = sbias[16 * mt + 4 * q + 1];
            float b2 = sbias[16 * mt + 4 * q + 2];
            float b3 = sbias[16 * mt + 4 * q + 3];
            float sj[4] = {0.f, 0.f, 0.f, 0.f};
            float qj[4] = {0.f, 0.f, 0.f, 0.f};
#pragma unroll
            for (int nt = 0; nt < 4; ++nt) {
                f32x4 a = acc[mt][nt];
                float a0 = a[0] + b0, a1 = a[1] + b1, a2 = a[2] + b2, a3 = a[3] + b3;
                int n = n0blk + n0w + 16 * nt + lane16;
                float v[4];
                if (!qo) {
                    v[0] = a0 + a1;            // add
                    v[1] = a2 * a3;            // mul
                    v[2] = 0.f; v[3] = 0.f;
                } else {
                    v[0] = __sinf(a0);         // sin
                    v[1] = __cosf(a1);         // cos
                    float e = __expf(-2.f * fabsf(a2));
                    v[2] = copysignf((1.f - e) / (1.f + e), a2);  // tanh
                    v[3] = a3;                 // identity
                }
                for (int i = 0; i < cnt; ++i) {
                    imgw[(size_t)(jb + j0 + i) * 4096 + n] = (u16)f2bf(v[i]);
                    sj[i] += v[i];
                    qj[i] += v[i] * v[i];
                }
            }
#pragma unroll
            for (int off = 1; off <= 8; off <<= 1) {
#pragma unroll
                for (int i = 0; i < 4; ++i) {
                    sj[i] += __shfl_xor(sj[i], off, 64);
                    qj[i] += __shfl_xor(qj[i], off, 64);
                }
            }
            if (lane16 == 0) {
                for (int i = 0; i < cnt; ++i) {
                    atomicAdd(&gsum[jb + j0 + i], sj[i]);
                    atomicAdd(&gss[jb + j0 + i],  qj[i]);
                }
            }
        }
    } else {
        // skip rows: j = 16*mt + 4*q + r, valid for mt < 3
#pragma unroll
        for (int mt = 0; mt < 3; ++mt) {
            int j0 = 16 * mt + 4 * q;
            float b0 = sbias[64 + j0 + 0];
            float b1 = sbias[64 + j0 + 1];
            float b2 = sbias[64 + j0 + 2];
            float b3 = sbias[64 + j0 + 3];
#pragma unroll
            for (int nt = 0; nt < 4; ++nt) {
                f32x4 a = acc[mt][nt];
                int n = n0blk + n0w + 16 * nt + lane16;
                skipw[(size_t)(jb + j0 + 0) * 4096 + n] = (u16)f2bf(a[0] + b0);
                skipw[(size_t)(jb + j0 + 1) * 4096 + n] = (u16)f2bf(a[1] + b1);
                skipw[(size_t)(jb + j0 + 2) * 4096 + n] = (u16)f2bf(a[2] + b2);
                skipw[(size_t)(jb + j0 + 3) * 4096 + n] = (u16)f2bf(a[3] + b3);
            }
        }
    }
}

// ---- K4: finalize: inorm(img) * renorm-chain + skip ----
__global__ __launch_bounds__(256) void k4_final(const u16* __restrict__ imgw,
                                                const u16* __restrict__ skipw,
                                                const float* __restrict__ gsum,
                                                const float* __restrict__ gss,
                                                float* __restrict__ out) {
    int j = blockIdx.x, b = blockIdx.y;
    int bj = b * 48 + j;
    float m = gsum[bj] * (1.f / 4096.f);
    float v = fmaxf(gss[bj] * (1.f / 4096.f) - m * m, 0.f);
    float rs = rsqrtf(v + EPS);
    float g = 1.f;
    float vv = v / (v + EPS);
    for (int k = 0; k < 47 - j; ++k) {
        g *= rsqrtf(vv + EPS);
        vv = vv / (vv + EPS);
    }
    float sc = rs * g;
    const u16* ir = imgw  + (size_t)bj * 4096;
    const u16* sr = skipw + (size_t)bj * 4096;
    float* orow = out + (size_t)bj * 4096;
    int t = threadIdx.x;
#pragma unroll
    for (int i = 0; i < 2; ++i) {
        int idx = t * 8 + i * 2048;
        uint4 iv = *(const uint4*)(ir + idx);
        uint4 sv = *(const uint4*)(sr + idx);
        const u32* ih = (const u32*)&iv;
        const u32* sh = (const u32*)&sv;
        float o[8];
#pragma unroll
        for (int e = 0; e < 4; ++e) {
            float i_lo = bf2f(ih[e] & 0xFFFFu), i_hi = bf2f(ih[e] >> 16);
            float s_lo = bf2f(sh[e] & 0xFFFFu), s_hi = bf2f(sh[e] >> 16);
            o[2 * e]     = (i_lo - m) * sc + s_lo;
            o[2 * e + 1] = (i_hi - m) * sc + s_hi;
        }
        *(float4*)(orow + idx)     = make_float4(o[0], o[1], o[2], o[3]);
        *(float4*)(orow + idx + 4) = make_float4(o[4], o[5], o[6], o[7]);
    }
}

extern "C" void kernel_launch(void* const* d_in, const int* in_sizes, int n_in,
                              void* d_out, int out_size, void* d_ws, size_t ws_size,
                              hipStream_t stream) {
    const float* x   = (const float*)d_in[0];   // [64,256,4096]
    const float* wch = (const float*)d_in[1];   // [64,256]
    const float* wdn = (const float*)d_in[2];   // [48,256]
    float* out = (float*)d_out;                 // [64,48,4096] fp32

    float* mean  = (float*)d_ws;                        // 16384
    float* rstd  = mean + 16384;                        // 16384
    float* bias  = rstd + 16384;                        // 64*128
    float* gsum  = bias + 64 * 128;                     // 3072
    float* gss   = gsum + 3072;                         // 3072
    u16*   Wc    = (u16*)(gss + 3072);                  // 64*128*256 bf16 (4 MB)
    u16*   imgw  = Wc + (size_t)64 * 128 * 256;         // 64*48*4096 bf16 (25 MB)
    u16*   skipw = imgw + (size_t)64 * 48 * 4096;       // 64*48*4096 bf16 (25 MB)

    k1_stats<<<dim3(16384), dim3(256), 0, stream>>>(x, mean, rstd);
    k2_prep<<<dim3(64), dim3(256), 0, stream>>>(wch, wdn, mean, rstd, Wc, bias, gsum, gss);
    k3_main<<<dim3(32, 64), dim3(256), 0, stream>>>(x, Wc, bias, imgw, skipw, gsum, gss);
    k4_final<<<dim3(48, 64), dim3(256), 0, stream>>>(imgw, skipw, gsum, gss, out);
}

// Round 3
// 505.095 us; speedup vs baseline: 1.6740x; 1.0917x over previous
//
#include <hip/hip_runtime.h>
#include <hip/hip_bf16.h>

#define EPS 1e-5f

typedef unsigned int u32;
typedef unsigned short u16;
typedef __attribute__((ext_vector_type(8))) short bf16x8;
typedef __attribute__((ext_vector_type(4))) float f32x4;

__device__ __forceinline__ u32 f2bf(float f) {
    u32 u = __float_as_uint(f);
    u += 0x7FFFu + ((u >> 16) & 1u);      // RNE
    return u >> 16;
}
__device__ __forceinline__ float bf2f(u32 h) {
    return __uint_as_float(h << 16);
}

// ---- K1: per (b,c) mean / rstd over L ----  (unchanged: near BW floor)
__global__ __launch_bounds__(256) void k1_stats(const float* __restrict__ x,
                                                float* __restrict__ mean,
                                                float* __restrict__ rstd) {
    int row = blockIdx.x;                       // b*256 + c
    const float* xr = x + (size_t)row * 4096;
    int t = threadIdx.x;
    float s = 0.f, ss = 0.f;
#pragma unroll
    for (int i = 0; i < 4; ++i) {
        float4 v = *(const float4*)(xr + t * 4 + i * 1024);
        s  += v.x + v.y + v.z + v.w;
        ss += v.x * v.x + v.y * v.y + v.z * v.z + v.w * v.w;
    }
    for (int off = 32; off > 0; off >>= 1) {
        s  += __shfl_down(s, off, 64);
        ss += __shfl_down(ss, off, 64);
    }
    __shared__ float red[8];
    int wid = t >> 6, lane = t & 63;
    if (lane == 0) { red[wid * 2] = s; red[wid * 2 + 1] = ss; }
    __syncthreads();
    if (t == 0) {
        float S  = red[0] + red[2] + red[4] + red[6];
        float SS = red[1] + red[3] + red[5] + red[7];
        float m = S * (1.f / 4096.f);
        float v = fmaxf(SS * (1.f / 4096.f) - m * m, 0.f);
        mean[row] = m;
        rstd[row] = rsqrtf(v + EPS);
    }
}

// ---- K2 (REWRITTEN): parallel rows, ONE barrier, coalesced bf16 stores ----
// Phase 1: thread c computes softmax stats over o (b-independent) + loads mean/rstd -> LDS.
// Phase 2: half-wave per row: 8 rows per pass, 16 passes; lane li covers c = li*8..li*8+7;
//          uint4 (8 x bf16) coalesced store; bias via 32-lane shuffle reduction.
__global__ __launch_bounds__(256) void k2_prep(const float* __restrict__ wch,
                                               const float* __restrict__ wdn,
                                               const float* __restrict__ mean,
                                               const float* __restrict__ rstd,
                                               u16* __restrict__ Wc,
                                               float* __restrict__ bias,
                                               float* __restrict__ gsum,
                                               float* __restrict__ gss) {
    int b = blockIdx.x, t = threadIdx.x;
    __shared__ float smx[256], sinv[256], ssc[256], smn[256];
    {
        int c = t;
        float mx = -1e30f;
        for (int o = 0; o < 64; ++o) mx = fmaxf(mx, wch[o * 256 + c]);
        float sum = 0.f;
        for (int o = 0; o < 64; ++o) sum += __expf(wch[o * 256 + c] - mx);
        smx[c] = mx; sinv[c] = 1.f / sum;
        ssc[c] = rstd[b * 256 + c];
        smn[c] = mean[b * 256 + c];
    }
    __syncthreads();

    int lane = t & 63, w = t >> 6;
    int sub = lane >> 5, li = lane & 31;     // half-wave id, lane-in-half
    int c8 = li * 8;
    u16* Wb = Wc + (size_t)b * 128 * 256;
#pragma unroll 4
    for (int j = 0; j < 16; ++j) {
        int r = j * 8 + w * 2 + sub;         // 0..127
        float p = 0.f;
        u32 packed[4];
#pragma unroll
        for (int e = 0; e < 4; ++e) {
            u32 lohi[2];
#pragma unroll
            for (int h = 0; h < 2; ++h) {
                int c = c8 + 2 * e + h;
                float wv;
                if (r < 64)       wv = __expf(wch[r * 256 + c] - smx[c]) * sinv[c];
                else if (r < 112) wv = wdn[(r - 64) * 256 + c];
                else              wv = 0.f;
                u32 hb = f2bf(wv * ssc[c]);
                lohi[h] = hb;
                p += bf2f(hb) * smn[c];
            }
            packed[e] = lohi[0] | (lohi[1] << 16);
        }
        *(uint4*)&Wb[r * 256 + c8] = *(uint4*)packed;
#pragma unroll
        for (int off = 1; off <= 16; off <<= 1) p += __shfl_xor(p, off, 64);
        if (li == 0) bias[b * 128 + r] = -p;
    }
    if (t < 48) { gsum[b * 48 + t] = 0.f; gss[b * 48 + t] = 0.f; }
}

// ---- K3: MFMA GEMM P[128][128] = Wc[b] @ x-tile + bias, fused symbolic funcs + stats ----
#define LSTR 36
__global__ __launch_bounds__(256, 4) void k3_main(const float* __restrict__ x,
                                                  const u16* __restrict__ Wc,
                                                  const float* __restrict__ bias,
                                                  u16* __restrict__ imgw,
                                                  u16* __restrict__ skipw,
                                                  float* __restrict__ gsum,
                                                  float* __restrict__ gss) {
    int lt = blockIdx.x;          // 0..31  (128-wide l tiles)
    int b  = blockIdx.y;          // 0..63
    int n0blk = lt * 128;
    int t = threadIdx.x;
    int w = t >> 6, u = t & 63;
    int lane16 = u & 15, q = u >> 4;
    int m0  = (w & 1) * 64;       // wave m-quadrant
    int n0w = (w >> 1) * 64;      // wave n-quadrant

    __shared__ u32 Wl[128 * LSTR];
    __shared__ u32 xTl[128 * LSTR];
    __shared__ float sbias[128];

    if (t < 128) sbias[t] = bias[b * 128 + t];

    f32x4 acc[4][4];
#pragma unroll
    for (int mt = 0; mt < 4; ++mt)
#pragma unroll
        for (int nt = 0; nt < 4; ++nt) acc[mt][nt] = (f32x4){0.f, 0.f, 0.f, 0.f};

    const float* xb = x + (size_t)b * 256 * 4096 + n0blk;
    const u16* Wb = Wc + (size_t)b * 128 * 256;

    for (int cc = 0; cc < 4; ++cc) {
        int c0 = cc * 64;
        if (cc) __syncthreads();
#pragma unroll
        for (int p = 0; p < 4; ++p) {
            int sl = t + 256 * p;
            int m = sl >> 3, kq = sl & 7;
            uint4 v = *(const uint4*)(Wb + m * 256 + c0 + 8 * kq);
            *(uint4*)&Wl[m * LSTR + 4 * kq] = v;
        }
#pragma unroll
        for (int p = 0; p < 4; ++p) {
            int sl = t + 256 * p;
            int kp = sl & 31, nqq = sl >> 5;
            const float* xr = xb + (size_t)(c0 + 2 * kp) * 4096 + 4 * nqq;
            float4 r0 = *(const float4*)xr;
            float4 r1 = *(const float4*)(xr + 4096);
            int base = (4 * nqq) * LSTR + kp;
            xTl[base]            = f2bf(r0.x) | (f2bf(r1.x) << 16);
            xTl[base + LSTR]     = f2bf(r0.y) | (f2bf(r1.y) << 16);
            xTl[base + 2 * LSTR] = f2bf(r0.z) | (f2bf(r1.z) << 16);
            xTl[base + 3 * LSTR] = f2bf(r0.w) | (f2bf(r1.w) << 16);
        }
        __syncthreads();
#pragma unroll
        for (int kk = 0; kk < 2; ++kk) {
            int kwo = kk * 16 + q * 4;
            bf16x8 af[4], bfr[4];
#pragma unroll
            for (int mt = 0; mt < 4; ++mt)
                af[mt] = *(bf16x8*)&Wl[(m0 + 16 * mt + lane16) * LSTR + kwo];
#pragma unroll
            for (int nt = 0; nt < 4; ++nt)
                bfr[nt] = *(bf16x8*)&xTl[(n0w + 16 * nt + lane16) * LSTR + kwo];
#pragma unroll
            for (int mt = 0; mt < 4; ++mt)
#pragma unroll
                for (int nt = 0; nt < 4; ++nt)
                    acc[mt][nt] = __builtin_amdgcn_mfma_f32_16x16x32_bf16(af[mt], bfr[nt], acc[mt][nt], 0, 0, 0);
        }
    }
    __syncthreads();

    int jb = b * 48;
    if (m0 == 0) {
        int g2 = q >> 1, qo = q & 1;
#pragma unroll
        for (int mt = 0; mt < 4; ++mt) {
            int g = 2 * mt + g2;
            int j0 = 6 * g + (qo ? 2 : 0);
            int cnt = qo ? 4 : 2;
            float b0 = sbias[16 * mt + 4 * q + 0];
            float b1 = sbias[16 * mt + 4 * q + 1];
            float b2 = sbias[16 * mt + 4 * q + 2];
            float b3 = sbias[16 * mt + 4 * q + 3];
            float sj[4] = {0.f, 0.f, 0.f, 0.f};
            float qj[4] = {0.f, 0.f, 0.f, 0.f};
#pragma unroll
            for (int nt = 0; nt < 4; ++nt) {
                f32x4 a = acc[mt][nt];
                float a0 = a[0] + b0, a1 = a[1] + b1, a2 = a[2] + b2, a3 = a[3] + b3;
                int n = n0blk + n0w + 16 * nt + lane16;
                float v[4];
                if (!qo) {
                    v[0] = a0 + a1;
                    v[1] = a2 * a3;
                    v[2] = 0.f; v[3] = 0.f;
                } else {
                    v[0] = __sinf(a0);
                    v[1] = __cosf(a1);
                    float e = __expf(-2.f * fabsf(a2));
                    v[2] = copysignf((1.f - e) / (1.f + e), a2);
                    v[3] = a3;
                }
                for (int i = 0; i < cnt; ++i) {
                    imgw[(size_t)(jb + j0 + i) * 4096 + n] = (u16)f2bf(v[i]);
                    sj[i] += v[i];
                    qj[i] += v[i] * v[i];
                }
            }
#pragma unroll
            for (int off = 1; off <= 8; off <<= 1) {
#pragma unroll
                for (int i = 0; i < 4; ++i) {
                    sj[i] += __shfl_xor(sj[i], off, 64);
                    qj[i] += __shfl_xor(qj[i], off, 64);
                }
            }
            if (lane16 == 0) {
                for (int i = 0; i < cnt; ++i) {
                    atomicAdd(&gsum[jb + j0 + i], sj[i]);
                    atomicAdd(&gss[jb + j0 + i],  qj[i]);
                }
            }
        }
    } else {
#pragma unroll
        for (int mt = 0; mt < 3; ++mt) {
            int j0 = 16 * mt + 4 * q;
            float b0 = sbias[64 + j0 + 0];
            float b1 = sbias[64 + j0 + 1];
            float b2 = sbias[64 + j0 + 2];
            float b3 = sbias[64 + j0 + 3];
#pragma unroll
            for (int nt = 0; nt < 4; ++nt) {
                f32x4 a = acc[mt][nt];
                int n = n0blk + n0w + 16 * nt + lane16;
                skipw[(size_t)(jb + j0 + 0) * 4096 + n] = (u16)f2bf(a[0] + b0);
                skipw[(size_t)(jb + j0 + 1) * 4096 + n] = (u16)f2bf(a[1] + b1);
                skipw[(size_t)(jb + j0 + 2) * 4096 + n] = (u16)f2bf(a[2] + b2);
                skipw[(size_t)(jb + j0 + 3) * 4096 + n] = (u16)f2bf(a[3] + b3);
            }
        }
    }
}

// ---- K4: finalize: inorm(img) * renorm-chain + skip ----  (unchanged: at BW floor)
__global__ __launch_bounds__(256) void k4_final(const u16* __restrict__ imgw,
                                                const u16* __restrict__ skipw,
                                                const float* __restrict__ gsum,
                                                const float* __restrict__ gss,
                                                float* __restrict__ out) {
    int j = blockIdx.x, b = blockIdx.y;
    int bj = b * 48 + j;
    float m = gsum[bj] * (1.f / 4096.f);
    float v = fmaxf(gss[bj] * (1.f / 4096.f) - m * m, 0.f);
    float rs = rsqrtf(v + EPS);
    float g = 1.f;
    float vv = v / (v + EPS);
    for (int k = 0; k < 47 - j; ++k) {
        g *= rsqrtf(vv + EPS);
        vv = vv / (vv + EPS);
    }
    float sc = rs * g;
    const u16* ir = imgw  + (size_t)bj * 4096;
    const u16* sr = skipw + (size_t)bj * 4096;
    float* orow = out + (size_t)bj * 4096;
    int t = threadIdx.x;
#pragma unroll
    for (int i = 0; i < 2; ++i) {
        int idx = t * 8 + i * 2048;
        uint4 iv = *(const uint4*)(ir + idx);
        uint4 sv = *(const uint4*)(sr + idx);
        const u32* ih = (const u32*)&iv;
        const u32* sh = (const u32*)&sv;
        float o[8];
#pragma unroll
        for (int e = 0; e < 4; ++e) {
            float i_lo = bf2f(ih[e] & 0xFFFFu), i_hi = bf2f(ih[e] >> 16);
            float s_lo = bf2f(sh[e] & 0xFFFFu), s_hi = bf2f(sh[e] >> 16);
            o[2 * e]     = (i_lo - m) * sc + s_lo;
            o[2 * e + 1] = (i_hi - m) * sc + s_hi;
        }
        *(float4*)(orow + idx)     = make_float4(o[0], o[1], o[2], o[3]);
        *(float4*)(orow + idx + 4) = make_float4(o[4], o[5], o[6], o[7]);
    }
}

extern "C" void kernel_launch(void* const* d_in, const int* in_sizes, int n_in,
                              void* d_out, int out_size, void* d_ws, size_t ws_size,
                              hipStream_t stream) {
    const float* x   = (const float*)d_in[0];   // [64,256,4096]
    const float* wch = (const float*)d_in[1];   // [64,256]
    const float* wdn = (const float*)d_in[2];   // [48,256]
    float* out = (float*)d_out;                 // [64,48,4096] fp32

    float* mean  = (float*)d_ws;                        // 16384
    float* rstd  = mean + 16384;                        // 16384
    float* bias  = rstd + 16384;                        // 64*128
    float* gsum  = bias + 64 * 128;                     // 3072
    float* gss   = gsum + 3072;                         // 3072
    u16*   Wc    = (u16*)(gss + 3072);                  // 64*128*256 bf16 (4 MB)
    u16*   imgw  = Wc + (size_t)64 * 128 * 256;         // 64*48*4096 bf16 (25 MB)
    u16*   skipw = imgw + (size_t)64 * 48 * 4096;       // 64*48*4096 bf16 (25 MB)

    k1_stats<<<dim3(16384), dim3(256), 0, stream>>>(x, mean, rstd);
    k2_prep<<<dim3(64), dim3(256), 0, stream>>>(wch, wdn, mean, rstd, Wc, bias, gsum, gss);
    k3_main<<<dim3(32, 64), dim3(256), 0, stream>>>(x, Wc, bias, imgw, skipw, gsum, gss);
    k4_final<<<dim3(48, 64), dim3(256), 0, stream>>>(imgw, skipw, gsum, gss, out);
}